// Round 5
// baseline (88.770 us; speedup 1.0000x reference)
//
#include <hip/hip_runtime.h>

#define B_ 2
#define C_ 64
#define H_ 192
#define W_ 384
#define K_ 8
constexpr int HW_ = H_ * W_;
constexpr int CHW_ = C_ * HW_;
constexpr int NP_ = B_ * HW_;           // 147456
constexpr int NBLK_ = NP_ / 64;         // 2304, %8==0
constexpr size_t WS_NEED_ = (size_t)NP_ * 64 * sizeof(float);  // 37.7 MB NHWC feat_t

// =================== K1: NCHW -> NHWC transpose ===================
__global__ __launch_bounds__(256) void transpose_kernel(
    const float* __restrict__ feat, float* __restrict__ ft) {
  __shared__ float lds[64 * 65];
  const int tid = threadIdx.x;
  const int lane = tid & 63;
  const int wv = tid >> 6;
  const int p0 = blockIdx.x * 64;
  const int b = p0 / HW_;
  const int hw0 = p0 - b * HW_;
  const float* fb = feat + (size_t)b * CHW_;
#pragma unroll
  for (int cc = 0; cc < 16; ++cc) {
    const int c = wv * 16 + cc;
    lds[lane * 65 + c] = fb[(size_t)c * HW_ + hw0 + lane];   // coalesced 256B
  }
  __syncthreads();
#pragma unroll
  for (int i = 0; i < 16; ++i) {
    const int row = i * 4 + wv;
    ft[(size_t)(p0 + row) * 64 + lane] = lds[row * 65 + lane];  // coalesced 256B
  }
}

// =================== K2: conv + softmax + gather + epilogue ===================
// block = 256 thr = 4 waves, 64 pixels.
// LDS floats: [0,4096) rec4 float4[16][64] {w0,off0,w1,off1}; [4096,8256) res[64][65].
// conv partials [24][4][64] = [0,6144) aliased (dead before rec/res written).
__global__ __launch_bounds__(256) void fusedg_kernel(
    const float* __restrict__ feat, const int* __restrict__ mask,
    const float* __restrict__ Wo, const float* __restrict__ bo,
    const float* __restrict__ Ww, const float* __restrict__ bw,
    const float* __restrict__ ws, float* __restrict__ out) {
  __shared__ float smem[8256];        // 33024 B
  float4* rw4 = (float4*)smem;
  float* resb = smem + 4096;

  const int tid = threadIdx.x;
  const int lane = tid & 63;
  const int wv = tid >> 6;
  const int bid = blockIdx.x;
  const int sb = (bid & 7) * (NBLK_ / 8) + (bid >> 3);   // bijective XCD swizzle
  const int p0 = sb * 64;
  const int b = p0 / HW_;
  const int hw0 = p0 - b * HW_;
  const size_t bCHW = (size_t)b * CHW_;
  const float* fb = feat + bCHW;

  // ---- phase A: conv partials (wave = 16 channels, lane = pixel) ----
  float pacc[24];
  float fv[16];                        // cached feat values for epilogue
#pragma unroll
  for (int j = 0; j < 24; ++j) pacc[j] = 0.f;
#pragma unroll
  for (int cc = 0; cc < 16; ++cc) {
    const int c = wv * 16 + cc;                       // wave-uniform -> s_load weights
    const float v = fb[(size_t)c * HW_ + hw0 + lane]; // coalesced
    fv[cc] = v;
#pragma unroll
    for (int j = 0; j < 16; ++j) pacc[j] = fmaf(Wo[j * C_ + c], v, pacc[j]);
#pragma unroll
    for (int j = 0; j < 8; ++j) pacc[16 + j] = fmaf(Ww[j * C_ + c], v, pacc[16 + j]);
  }
#pragma unroll
  for (int j = 0; j < 24; ++j) smem[j * 256 + wv * 64 + lane] = pacc[j];
  __syncthreads();

  // ---- phase B: cross-wave reduce (every wave, lane = pixel) ----
  float acc[24];
#pragma unroll
  for (int j = 0; j < 24; ++j)
    acc[j] = (smem[j * 256 + lane] + smem[j * 256 + 64 + lane]) +
             (smem[j * 256 + 128 + lane] + smem[j * 256 + 192 + lane]);
  __syncthreads();   // conv region dead after this barrier

#pragma unroll
  for (int j = 0; j < 16; ++j) acc[j] += bo[j];
#pragma unroll
  for (int j = 0; j < 8; ++j) acc[16 + j] += bw[j];

  // softmax + mask fold (lane = pixel)
  float m = acc[16];
#pragma unroll
  for (int k = 1; k < K_; ++k) m = fmaxf(m, acc[16 + k]);
  float s = 0.f;
#pragma unroll
  for (int k = 0; k < K_; ++k) s += __expf(acc[16 + k] - m);
  const float fm = (mask[p0 + lane] != 0) ? 1.f : 0.f;
  const float inv = fm / s;
  const bool act = (fm != 0.f);

  const int hw = hw0 + lane;
  const int y = hw / W_;
  const int x = hw - y * W_;
  const int bHW = b * HW_;

  // records for this wave's 16 pixels (lanes 16wv..16wv+15 own pixel = lane)
  if ((lane >> 4) == wv) {
    const int pxl = lane;
#pragma unroll
    for (int k = 0; k < K_; ++k) {
      const float wtk = __expf(acc[16 + k] - m) * inv;
      const float px = (float)x + acc[2 * k];
      const float py = (float)y + acc[2 * k + 1];
      const float x0f = floorf(px), y0f = floorf(py);
      const float wx = px - x0f, wy = py - y0f;
      const int x0 = (int)x0f, y0 = (int)y0f;
      const int x1 = x0 + 1, y1 = y0 + 1;
      const bool vx0 = ((unsigned)x0 < (unsigned)W_);
      const bool vx1 = ((unsigned)x1 < (unsigned)W_);
      const bool vy0 = ((unsigned)y0 < (unsigned)H_);
      const bool vy1 = ((unsigned)y1 < (unsigned)H_);
      const int cx0 = min(max(x0, 0), W_ - 1), cx1 = min(max(x1, 0), W_ - 1);
      const int cy0 = min(max(y0, 0), H_ - 1), cy1 = min(max(y1, 0), H_ - 1);
      const float w00 = wtk * (1.f - wx) * (1.f - wy) * ((vx0 && vy0) ? 1.f : 0.f);
      const float w01 = wtk * wx * (1.f - wy) * ((vx1 && vy0) ? 1.f : 0.f);
      const float w10 = wtk * (1.f - wx) * wy * ((vx0 && vy1) ? 1.f : 0.f);
      const float w11 = wtk * wx * wy * ((vx1 && vy1) ? 1.f : 0.f);
      // byte offsets into NHWC feat_t; masked pixels -> offset 0 (L1 broadcast), w=0
      const int o00 = act ? ((bHW + cy0 * W_ + cx0) << 8) : 0;
      const int o01 = act ? ((bHW + cy0 * W_ + cx1) << 8) : 0;
      const int o10 = act ? ((bHW + cy1 * W_ + cx0) << 8) : 0;
      const int o11 = act ? ((bHW + cy1 * W_ + cx1) << 8) : 0;
      float4 ra, rb;
      ra.x = w00; ra.y = __int_as_float(o00);
      ra.z = w01; ra.w = __int_as_float(o01);
      rb.x = w10; rb.y = __int_as_float(o10);
      rb.z = w11; rb.w = __int_as_float(o11);
      rw4[(k * 2 + 0) * 64 + pxl] = ra;
      rw4[(k * 2 + 1) * 64 + pxl] = rb;
    }
  }

  // ---- phase C: gather. lane = (pg, cg): 4 pixels x 16 channel-groups. ----
  // Each lane owns the full 4-corner sum for its (pixel, 4-channel group):
  // no shuffles, no branches; masked pixels read offset-0 (L1 hit) with w=0.
  const int pg = lane >> 4;            // 0..3
  const int cg = lane & 15;            // channel group of 4
  const int cgb = cg * 16;             // byte offset within a pixel's 256B row
  const char* ftb = (const char*)ws;

#pragma unroll 2
  for (int it = 0; it < 4; ++it) {
    const int pxl = wv * 16 + it * 4 + pg;     // own wave's records (lgkmcnt-ordered)
    float4 r = make_float4(0.f, 0.f, 0.f, 0.f);
#pragma unroll
    for (int k = 0; k < K_; ++k) {
      const float4 ra = rw4[(k * 2 + 0) * 64 + pxl];   // {w00,o00,w01,o01}
      const float4 rb = rw4[(k * 2 + 1) * 64 + pxl];   // {w10,o10,w11,o11}
      {
        const float4 v = *(const float4*)(ftb + (__float_as_int(ra.y) + cgb));
        r.x = fmaf(ra.x, v.x, r.x); r.y = fmaf(ra.x, v.y, r.y);
        r.z = fmaf(ra.x, v.z, r.z); r.w = fmaf(ra.x, v.w, r.w);
      }
      {
        const float4 v = *(const float4*)(ftb + (__float_as_int(ra.w) + cgb));
        r.x = fmaf(ra.z, v.x, r.x); r.y = fmaf(ra.z, v.y, r.y);
        r.z = fmaf(ra.z, v.z, r.z); r.w = fmaf(ra.z, v.w, r.w);
      }
      {
        const float4 v = *(const float4*)(ftb + (__float_as_int(rb.y) + cgb));
        r.x = fmaf(rb.x, v.x, r.x); r.y = fmaf(rb.x, v.y, r.y);
        r.z = fmaf(rb.x, v.z, r.z); r.w = fmaf(rb.x, v.w, r.w);
      }
      {
        const float4 v = *(const float4*)(ftb + (__float_as_int(rb.w) + cgb));
        r.x = fmaf(rb.z, v.x, r.x); r.y = fmaf(rb.z, v.y, r.y);
        r.z = fmaf(rb.z, v.z, r.z); r.w = fmaf(rb.z, v.w, r.w);
      }
    }
    const int base = pxl * 65 + cg * 4;        // stride-65 rows: scalar writes (align)
    resb[base + 0] = r.x; resb[base + 1] = r.y;
    resb[base + 2] = r.z; resb[base + 3] = r.w;
  }
  __syncthreads();

  // ---- phase D: epilogue, coalesced NCHW; feat from phase-A registers ----
#pragma unroll
  for (int cc = 0; cc < 16; ++cc) {
    const int c = wv * 16 + cc;
    const size_t off = bCHW + (size_t)c * HW_ + hw0 + lane;
    out[off] = fv[cc] + resb[lane * 65 + c];
  }
}

// =================== Fallback (ws-free, round-1 fused) ===================
__global__ __launch_bounds__(256) void fused_kernel(
    const float* __restrict__ feat, const int* __restrict__ mask,
    const float* __restrict__ Wo, const float* __restrict__ bo,
    const float* __restrict__ Ww, const float* __restrict__ bw,
    float* __restrict__ out) {
  const int p = blockIdx.x * blockDim.x + threadIdx.x;
  const int b = p / HW_;
  const int hw = p - b * HW_;
  const int y = hw / W_;
  const int x = hw - y * W_;
  const float* fb = feat + b * CHW_;
  float acc[24];
#pragma unroll
  for (int i = 0; i < 16; ++i) acc[i] = bo[i];
#pragma unroll
  for (int i = 0; i < 8; ++i) acc[16 + i] = bw[i];
#pragma unroll
  for (int c = 0; c < C_; ++c) {
    const float v = fb[c * HW_ + hw];
#pragma unroll
    for (int i = 0; i < 16; ++i) acc[i] = fmaf(Wo[i * C_ + c], v, acc[i]);
#pragma unroll
    for (int i = 0; i < 8; ++i) acc[16 + i] = fmaf(Ww[i * C_ + c], v, acc[16 + i]);
  }
  float m = acc[16];
#pragma unroll
  for (int k = 1; k < K_; ++k) m = fmaxf(m, acc[16 + k]);
  float wt[K_];
  float s = 0.f;
#pragma unroll
  for (int k = 0; k < K_; ++k) { wt[k] = __expf(acc[16 + k] - m); s += wt[k]; }
  const float fm = (mask[p] != 0) ? 1.f : 0.f;
  const float inv = fm / s;
#pragma unroll
  for (int k = 0; k < K_; ++k) wt[k] *= inv;
  float res[C_];
#pragma unroll
  for (int c = 0; c < C_; ++c) res[c] = 0.f;
  if (fm != 0.f) {
#pragma unroll
    for (int k = 0; k < K_; ++k) {
      const float px = (float)x + acc[2 * k];
      const float py = (float)y + acc[2 * k + 1];
      const float x0f = floorf(px), y0f = floorf(py);
      const float wx = px - x0f, wy = py - y0f;
      const int x0 = (int)x0f, y0 = (int)y0f;
      const int x1 = x0 + 1, y1 = y0 + 1;
      const bool vx0 = ((unsigned)x0 < (unsigned)W_);
      const bool vx1 = ((unsigned)x1 < (unsigned)W_);
      const bool vy0 = ((unsigned)y0 < (unsigned)H_);
      const bool vy1 = ((unsigned)y1 < (unsigned)H_);
      const int cx0 = min(max(x0, 0), W_ - 1), cx1 = min(max(x1, 0), W_ - 1);
      const int cy0 = min(max(y0, 0), H_ - 1), cy1 = min(max(y1, 0), H_ - 1);
      const float wk = wt[k];
      const float w00 = wk * (1.f - wx) * (1.f - wy) * ((vx0 && vy0) ? 1.f : 0.f);
      const float w01 = wk * wx * (1.f - wy) * ((vx1 && vy0) ? 1.f : 0.f);
      const float w10 = wk * (1.f - wx) * wy * ((vx0 && vy1) ? 1.f : 0.f);
      const float w11 = wk * wx * wy * ((vx1 && vy1) ? 1.f : 0.f);
      const int i00 = cy0 * W_ + cx0, i01 = cy0 * W_ + cx1;
      const int i10 = cy1 * W_ + cx0, i11 = cy1 * W_ + cx1;
#pragma unroll
      for (int c = 0; c < C_; ++c) {
        const float* fc = fb + c * HW_;
        res[c] += w00 * fc[i00] + w01 * fc[i01] + w10 * fc[i10] + w11 * fc[i11];
      }
    }
  }
#pragma unroll
  for (int c = 0; c < C_; ++c)
    out[b * CHW_ + c * HW_ + hw] = fb[c * HW_ + hw] + res[c];
}

extern "C" void kernel_launch(void* const* d_in, const int* in_sizes, int n_in,
                              void* d_out, int out_size, void* d_ws, size_t ws_size,
                              hipStream_t stream) {
  const float* feat = (const float*)d_in[0];
  const int* mask = (const int*)d_in[1];
  const float* Wo = (const float*)d_in[2];
  const float* bo = (const float*)d_in[3];
  const float* Ww = (const float*)d_in[4];
  const float* bw = (const float*)d_in[5];
  float* out = (float*)d_out;

  if (ws_size >= WS_NEED_) {
    float* ws = (float*)d_ws;
    hipLaunchKernelGGL(transpose_kernel, dim3(NBLK_), dim3(256), 0, stream,
                       feat, ws);
    hipLaunchKernelGGL(fusedg_kernel, dim3(NBLK_), dim3(256), 0, stream,
                       feat, mask, Wo, bo, Ww, bw, ws, out);
  } else {
    hipLaunchKernelGGL(fused_kernel, dim3(NP_ / 256), dim3(256), 0, stream,
                       feat, mask, Wo, bo, Ww, bw, out);
  }
}

// Round 6
// 70.850 us; speedup vs baseline: 1.2529x; 1.2529x over previous
//
#include <hip/hip_runtime.h>
#include <hip/hip_bf16.h>

#define B_ 2
#define C_ 64
#define H_ 192
#define W_ 384
#define K_ 8
constexpr int HW_ = H_ * W_;
constexpr int CHW_ = C_ * HW_;
constexpr int NP_ = B_ * HW_;           // 147456
constexpr int NBLK_ = NP_ / 64;         // 2304, %8==0
constexpr size_t WS_NEED_ = (size_t)NP_ * 64 * sizeof(unsigned short);  // 18.9 MB bf16 NHWC

// =================== K1: NCHW fp32 -> NHWC bf16 transpose ===================
__global__ __launch_bounds__(256) void transpose16_kernel(
    const float* __restrict__ feat, unsigned short* __restrict__ ft) {
  __shared__ float lds[64 * 65];
  const int tid = threadIdx.x;
  const int lane = tid & 63;
  const int wv = tid >> 6;
  const int p0 = blockIdx.x * 64;
  const int b = p0 / HW_;
  const int hw0 = p0 - b * HW_;
  const float* fb = feat + (size_t)b * CHW_;
#pragma unroll
  for (int cc = 0; cc < 16; ++cc) {
    const int c = wv * 16 + cc;
    lds[lane * 65 + c] = fb[(size_t)c * HW_ + hw0 + lane];   // coalesced 256B
  }
  __syncthreads();
  // pack 2 channels -> uint; 8 iterations; coalesced 256B uint stores
  uint* ft32 = (uint*)ft;
#pragma unroll
  for (int j = 0; j < 8; ++j) {
    const int idx = j * 256 + tid;       // uint index within block tile
    const int row = idx >> 5;            // pixel 0..63
    const int cp = idx & 31;             // channel pair
    __hip_bfloat16 h0 = __float2bfloat16(lds[row * 65 + 2 * cp]);
    __hip_bfloat16 h1 = __float2bfloat16(lds[row * 65 + 2 * cp + 1]);
    const uint u = (uint)*(unsigned short*)&h0 | ((uint)*(unsigned short*)&h1 << 16);
    ft32[(size_t)(p0 + row) * 32 + cp] = u;
  }
}

// =================== K2: conv + softmax + gather + epilogue ===================
// block = 256 thr = 4 waves, 64 pixels.
// LDS floats: [0,4096) rec4 float4[16][64] {w,off,w,off}; [4096,8256) res[64][65].
// conv partials [24][4][64] = [0,6144) aliased (dead before res written).
__global__ __launch_bounds__(256) void fusedg_kernel(
    const float* __restrict__ feat, const int* __restrict__ mask,
    const float* __restrict__ Wo, const float* __restrict__ bo,
    const float* __restrict__ Ww, const float* __restrict__ bw,
    const unsigned short* __restrict__ ws, float* __restrict__ out) {
  __shared__ float smem[8256];        // 33024 B
  float4* rw4 = (float4*)smem;
  float* resb = smem + 4096;

  const int tid = threadIdx.x;
  const int lane = tid & 63;
  const int wv = tid >> 6;
  const int bid = blockIdx.x;
  const int sb = (bid & 7) * (NBLK_ / 8) + (bid >> 3);   // bijective XCD swizzle
  const int p0 = sb * 64;
  const int b = p0 / HW_;
  const int hw0 = p0 - b * HW_;
  const size_t bCHW = (size_t)b * CHW_;
  const float* fb = feat + bCHW;

  // ---- phase A: conv partials (wave = 16 channels, lane = pixel) ----
  float pacc[24];
  float fv[16];                        // cached feat values for epilogue
#pragma unroll
  for (int j = 0; j < 24; ++j) pacc[j] = 0.f;
#pragma unroll
  for (int cc = 0; cc < 16; ++cc) {
    const int c = wv * 16 + cc;                       // wave-uniform -> s_load weights
    const float v = fb[(size_t)c * HW_ + hw0 + lane]; // coalesced
    fv[cc] = v;
#pragma unroll
    for (int j = 0; j < 16; ++j) pacc[j] = fmaf(Wo[j * C_ + c], v, pacc[j]);
#pragma unroll
    for (int j = 0; j < 8; ++j) pacc[16 + j] = fmaf(Ww[j * C_ + c], v, pacc[16 + j]);
  }
#pragma unroll
  for (int j = 0; j < 24; ++j) smem[j * 256 + wv * 64 + lane] = pacc[j];
  __syncthreads();

  // ---- phase B: cross-wave reduce (every wave, lane = pixel) ----
  float acc[24];
#pragma unroll
  for (int j = 0; j < 24; ++j)
    acc[j] = (smem[j * 256 + lane] + smem[j * 256 + 64 + lane]) +
             (smem[j * 256 + 128 + lane] + smem[j * 256 + 192 + lane]);
  __syncthreads();   // conv region dead after this barrier

#pragma unroll
  for (int j = 0; j < 16; ++j) acc[j] += bo[j];
#pragma unroll
  for (int j = 0; j < 8; ++j) acc[16 + j] += bw[j];

  // softmax + mask fold (lane = pixel)
  float m = acc[16];
#pragma unroll
  for (int k = 1; k < K_; ++k) m = fmaxf(m, acc[16 + k]);
  float s = 0.f;
#pragma unroll
  for (int k = 0; k < K_; ++k) s += __expf(acc[16 + k] - m);
  const float fm = (mask[p0 + lane] != 0) ? 1.f : 0.f;
  const float inv = fm / s;
  const bool act = (fm != 0.f);

  const int hw = hw0 + lane;
  const int y = hw / W_;
  const int x = hw - y * W_;
  const int bHW = b * HW_;

  // records for this wave's 16 pixels (lanes 16wv..16wv+15 own pixel = lane)
  if ((lane >> 4) == wv) {
    const int pxl = lane;
#pragma unroll
    for (int k = 0; k < K_; ++k) {
      const float wtk = __expf(acc[16 + k] - m) * inv;
      const float px = (float)x + acc[2 * k];
      const float py = (float)y + acc[2 * k + 1];
      const float x0f = floorf(px), y0f = floorf(py);
      const float wx = px - x0f, wy = py - y0f;
      const int x0 = (int)x0f, y0 = (int)y0f;
      const int x1 = x0 + 1, y1 = y0 + 1;
      const bool vx0 = ((unsigned)x0 < (unsigned)W_);
      const bool vx1 = ((unsigned)x1 < (unsigned)W_);
      const bool vy0 = ((unsigned)y0 < (unsigned)H_);
      const bool vy1 = ((unsigned)y1 < (unsigned)H_);
      const int cx0 = min(max(x0, 0), W_ - 1), cx1 = min(max(x1, 0), W_ - 1);
      const int cy0 = min(max(y0, 0), H_ - 1), cy1 = min(max(y1, 0), H_ - 1);
      const float w00 = wtk * (1.f - wx) * (1.f - wy) * ((vx0 && vy0) ? 1.f : 0.f);
      const float w01 = wtk * wx * (1.f - wy) * ((vx1 && vy0) ? 1.f : 0.f);
      const float w10 = wtk * (1.f - wx) * wy * ((vx0 && vy1) ? 1.f : 0.f);
      const float w11 = wtk * wx * wy * ((vx1 && vy1) ? 1.f : 0.f);
      // byte offsets into bf16 NHWC (128B rows); masked -> offset 0 (L1 hit), w=0
      const int o00 = act ? ((bHW + cy0 * W_ + cx0) << 7) : 0;
      const int o01 = act ? ((bHW + cy0 * W_ + cx1) << 7) : 0;
      const int o10 = act ? ((bHW + cy1 * W_ + cx0) << 7) : 0;
      const int o11 = act ? ((bHW + cy1 * W_ + cx1) << 7) : 0;
      float4 ra, rb;
      ra.x = w00; ra.y = __int_as_float(o00);
      ra.z = w01; ra.w = __int_as_float(o01);
      rb.x = w10; rb.y = __int_as_float(o10);
      rb.z = w11; rb.w = __int_as_float(o11);
      rw4[(k * 2 + 0) * 64 + pxl] = ra;
      rw4[(k * 2 + 1) * 64 + pxl] = rb;
    }
  }

  // ---- phase C: gather. lane = (pg, cg): 8 pixels x 8 channel-groups of 8 ch. ----
  // Branch-free; 8 loads staged in registers per k-pair for MLP.
  const int pg = lane >> 3;            // 0..7
  const int cg = lane & 7;             // channel group of 8 (bf16)
  const int cgb = cg * 16;             // byte offset within a pixel's 128B row
  const char* ftb = (const char*)ws;

#define ACC8(V, WT)                                                        \
  do {                                                                     \
    rr[0] = fmaf(WT, __uint_as_float((V).x << 16), rr[0]);                 \
    rr[1] = fmaf(WT, __uint_as_float((V).x & 0xffff0000u), rr[1]);         \
    rr[2] = fmaf(WT, __uint_as_float((V).y << 16), rr[2]);                 \
    rr[3] = fmaf(WT, __uint_as_float((V).y & 0xffff0000u), rr[3]);         \
    rr[4] = fmaf(WT, __uint_as_float((V).z << 16), rr[4]);                 \
    rr[5] = fmaf(WT, __uint_as_float((V).z & 0xffff0000u), rr[5]);         \
    rr[6] = fmaf(WT, __uint_as_float((V).w << 16), rr[6]);                 \
    rr[7] = fmaf(WT, __uint_as_float((V).w & 0xffff0000u), rr[7]);         \
  } while (0)

#pragma unroll
  for (int it = 0; it < 2; ++it) {
    const int pxl = wv * 16 + it * 8 + pg;
    float rr[8];
#pragma unroll
    for (int j = 0; j < 8; ++j) rr[j] = 0.f;
#pragma unroll
    for (int k2 = 0; k2 < 4; ++k2) {           // k pair: 8 staged loads in flight
      const float4 ra0 = rw4[((2 * k2 + 0) * 2 + 0) * 64 + pxl];
      const float4 rb0 = rw4[((2 * k2 + 0) * 2 + 1) * 64 + pxl];
      const float4 ra1 = rw4[((2 * k2 + 1) * 2 + 0) * 64 + pxl];
      const float4 rb1 = rw4[((2 * k2 + 1) * 2 + 1) * 64 + pxl];
      const uint4 v0 = *(const uint4*)(ftb + (__float_as_int(ra0.y) + cgb));
      const uint4 v1 = *(const uint4*)(ftb + (__float_as_int(ra0.w) + cgb));
      const uint4 v2 = *(const uint4*)(ftb + (__float_as_int(rb0.y) + cgb));
      const uint4 v3 = *(const uint4*)(ftb + (__float_as_int(rb0.w) + cgb));
      const uint4 v4 = *(const uint4*)(ftb + (__float_as_int(ra1.y) + cgb));
      const uint4 v5 = *(const uint4*)(ftb + (__float_as_int(ra1.w) + cgb));
      const uint4 v6 = *(const uint4*)(ftb + (__float_as_int(rb1.y) + cgb));
      const uint4 v7 = *(const uint4*)(ftb + (__float_as_int(rb1.w) + cgb));
      ACC8(v0, ra0.x); ACC8(v1, ra0.z); ACC8(v2, rb0.x); ACC8(v3, rb0.z);
      ACC8(v4, ra1.x); ACC8(v5, ra1.z); ACC8(v6, rb1.x); ACC8(v7, rb1.z);
    }
    const int base = pxl * 65 + cg * 8;
#pragma unroll
    for (int j = 0; j < 8; ++j) resb[base + j] = rr[j];   // 2-way banks (free)
  }
#undef ACC8
  __syncthreads();

  // ---- phase D: epilogue, coalesced NCHW; feat from phase-A registers ----
#pragma unroll
  for (int cc = 0; cc < 16; ++cc) {
    const int c = wv * 16 + cc;
    const size_t off = bCHW + (size_t)c * HW_ + hw0 + lane;
    out[off] = fv[cc] + resb[lane * 65 + c];
  }
}

// =================== Fallback (ws-free, round-1 fused) ===================
__global__ __launch_bounds__(256) void fused_kernel(
    const float* __restrict__ feat, const int* __restrict__ mask,
    const float* __restrict__ Wo, const float* __restrict__ bo,
    const float* __restrict__ Ww, const float* __restrict__ bw,
    float* __restrict__ out) {
  const int p = blockIdx.x * blockDim.x + threadIdx.x;
  const int b = p / HW_;
  const int hw = p - b * HW_;
  const int y = hw / W_;
  const int x = hw - y * W_;
  const float* fb = feat + b * CHW_;
  float acc[24];
#pragma unroll
  for (int i = 0; i < 16; ++i) acc[i] = bo[i];
#pragma unroll
  for (int i = 0; i < 8; ++i) acc[16 + i] = bw[i];
#pragma unroll
  for (int c = 0; c < C_; ++c) {
    const float v = fb[c * HW_ + hw];
#pragma unroll
    for (int i = 0; i < 16; ++i) acc[i] = fmaf(Wo[i * C_ + c], v, acc[i]);
#pragma unroll
    for (int i = 0; i < 8; ++i) acc[16 + i] = fmaf(Ww[i * C_ + c], v, acc[16 + i]);
  }
  float m = acc[16];
#pragma unroll
  for (int k = 1; k < K_; ++k) m = fmaxf(m, acc[16 + k]);
  float wt[K_];
  float s = 0.f;
#pragma unroll
  for (int k = 0; k < K_; ++k) { wt[k] = __expf(acc[16 + k] - m); s += wt[k]; }
  const float fm = (mask[p] != 0) ? 1.f : 0.f;
  const float inv = fm / s;
#pragma unroll
  for (int k = 0; k < K_; ++k) wt[k] *= inv;
  float res[C_];
#pragma unroll
  for (int c = 0; c < C_; ++c) res[c] = 0.f;
  if (fm != 0.f) {
#pragma unroll
    for (int k = 0; k < K_; ++k) {
      const float px = (float)x + acc[2 * k];
      const float py = (float)y + acc[2 * k + 1];
      const float x0f = floorf(px), y0f = floorf(py);
      const float wx = px - x0f, wy = py - y0f;
      const int x0 = (int)x0f, y0 = (int)y0f;
      const int x1 = x0 + 1, y1 = y0 + 1;
      const bool vx0 = ((unsigned)x0 < (unsigned)W_);
      const bool vx1 = ((unsigned)x1 < (unsigned)W_);
      const bool vy0 = ((unsigned)y0 < (unsigned)H_);
      const bool vy1 = ((unsigned)y1 < (unsigned)H_);
      const int cx0 = min(max(x0, 0), W_ - 1), cx1 = min(max(x1, 0), W_ - 1);
      const int cy0 = min(max(y0, 0), H_ - 1), cy1 = min(max(y1, 0), H_ - 1);
      const float wk = wt[k];
      const float w00 = wk * (1.f - wx) * (1.f - wy) * ((vx0 && vy0) ? 1.f : 0.f);
      const float w01 = wk * wx * (1.f - wy) * ((vx1 && vy0) ? 1.f : 0.f);
      const float w10 = wk * (1.f - wx) * wy * ((vx0 && vy1) ? 1.f : 0.f);
      const float w11 = wk * wx * wy * ((vx1 && vy1) ? 1.f : 0.f);
      const int i00 = cy0 * W_ + cx0, i01 = cy0 * W_ + cx1;
      const int i10 = cy1 * W_ + cx0, i11 = cy1 * W_ + cx1;
#pragma unroll
      for (int c = 0; c < C_; ++c) {
        const float* fc = fb + c * HW_;
        res[c] += w00 * fc[i00] + w01 * fc[i01] + w10 * fc[i10] + w11 * fc[i11];
      }
    }
  }
#pragma unroll
  for (int c = 0; c < C_; ++c)
    out[b * CHW_ + c * HW_ + hw] = fb[c * HW_ + hw] + res[c];
}

extern "C" void kernel_launch(void* const* d_in, const int* in_sizes, int n_in,
                              void* d_out, int out_size, void* d_ws, size_t ws_size,
                              hipStream_t stream) {
  const float* feat = (const float*)d_in[0];
  const int* mask = (const int*)d_in[1];
  const float* Wo = (const float*)d_in[2];
  const float* bo = (const float*)d_in[3];
  const float* Ww = (const float*)d_in[4];
  const float* bw = (const float*)d_in[5];
  float* out = (float*)d_out;

  if (ws_size >= WS_NEED_) {
    unsigned short* ws = (unsigned short*)d_ws;
    hipLaunchKernelGGL(transpose16_kernel, dim3(NBLK_), dim3(256), 0, stream,
                       feat, ws);
    hipLaunchKernelGGL(fusedg_kernel, dim3(NBLK_), dim3(256), 0, stream,
                       feat, mask, Wo, bo, Ww, bw, ws, out);
  } else {
    hipLaunchKernelGGL(fused_kernel, dim3(NP_ / 256), dim3(256), 0, stream,
                       feat, mask, Wo, bo, Ww, bw, out);
  }
}

// Round 7
// 68.507 us; speedup vs baseline: 1.2958x; 1.0342x over previous
//
#include <hip/hip_runtime.h>
#include <hip/hip_bf16.h>

#define B_ 2
#define C_ 64
#define H_ 192
#define W_ 384
#define K_ 8
constexpr int HW_ = H_ * W_;
constexpr int CHW_ = C_ * HW_;
constexpr int NP_ = B_ * HW_;           // 147456
constexpr int NBLK_ = NP_ / 64;         // 2304, %8==0
constexpr size_t WS_NEED_ = (size_t)NP_ * 64 * sizeof(unsigned short);  // 18.9 MB bf16 NHWC

// =================== K1: NCHW fp32 -> NHWC bf16 transpose ===================
__global__ __launch_bounds__(256) void transpose16_kernel(
    const float* __restrict__ feat, unsigned short* __restrict__ ft) {
  __shared__ float lds[64 * 65];
  const int tid = threadIdx.x;
  const int lane = tid & 63;
  const int wv = tid >> 6;
  const int p0 = blockIdx.x * 64;
  const int b = p0 / HW_;
  const int hw0 = p0 - b * HW_;
  const float* fb = feat + (size_t)b * CHW_;
#pragma unroll
  for (int cc = 0; cc < 16; ++cc) {
    const int c = wv * 16 + cc;
    lds[lane * 65 + c] = fb[(size_t)c * HW_ + hw0 + lane];   // coalesced 256B
  }
  __syncthreads();
  uint* ft32 = (uint*)ft;
#pragma unroll
  for (int j = 0; j < 8; ++j) {
    const int idx = j * 256 + tid;       // uint index within block tile
    const int row = idx >> 5;            // pixel 0..63
    const int cp = idx & 31;             // channel pair
    __hip_bfloat16 h0 = __float2bfloat16(lds[row * 65 + 2 * cp]);
    __hip_bfloat16 h1 = __float2bfloat16(lds[row * 65 + 2 * cp + 1]);
    const uint u = (uint)*(unsigned short*)&h0 | ((uint)*(unsigned short*)&h1 << 16);
    ft32[(size_t)(p0 + row) * 32 + cp] = u;
  }
}

// =================== K2: conv + softmax + compacted gather + epilogue ===================
// block = 256 thr = 4 waves, 64 pixels.
// LDS floats: [0,4096) rec4 float4[16][64] {w,off,w,off}; [4096,8256) res[64][65];
// [8256,8320) actlist (ints). conv partials [24][4][64]=[0,6144) aliased.
__global__ __launch_bounds__(256) void fusedg_kernel(
    const float* __restrict__ feat, const int* __restrict__ mask,
    const float* __restrict__ Wo, const float* __restrict__ bo,
    const float* __restrict__ Ww, const float* __restrict__ bw,
    const unsigned short* __restrict__ ws, float* __restrict__ out) {
  __shared__ float smem[8320];        // 33280 B
  float4* rw4 = (float4*)smem;
  float* resb = smem + 4096;
  int* actl = (int*)(smem + 8256);

  const int tid = threadIdx.x;
  const int lane = tid & 63;
  const int wv = tid >> 6;
  const int bid = blockIdx.x;
  const int sb = (bid & 7) * (NBLK_ / 8) + (bid >> 3);   // bijective XCD swizzle
  const int p0 = sb * 64;
  const int b = p0 / HW_;
  const int hw0 = p0 - b * HW_;
  const size_t bCHW = (size_t)b * CHW_;
  const float* fb = feat + bCHW;

  // ---- phase A: conv partials (wave = 16 channels, lane = pixel) ----
  float pacc[24];
  float fv[16];                        // cached feat values for epilogue
#pragma unroll
  for (int j = 0; j < 24; ++j) pacc[j] = 0.f;
#pragma unroll
  for (int cc = 0; cc < 16; ++cc) {
    const int c = wv * 16 + cc;                       // wave-uniform -> s_load weights
    const float v = fb[(size_t)c * HW_ + hw0 + lane]; // coalesced
    fv[cc] = v;
#pragma unroll
    for (int j = 0; j < 16; ++j) pacc[j] = fmaf(Wo[j * C_ + c], v, pacc[j]);
#pragma unroll
    for (int j = 0; j < 8; ++j) pacc[16 + j] = fmaf(Ww[j * C_ + c], v, pacc[16 + j]);
  }
#pragma unroll
  for (int j = 0; j < 24; ++j) smem[j * 256 + wv * 64 + lane] = pacc[j];
  __syncthreads();

  // ---- phase B: cross-wave reduce (every wave, lane = pixel) ----
  float acc[24];
#pragma unroll
  for (int j = 0; j < 24; ++j)
    acc[j] = (smem[j * 256 + lane] + smem[j * 256 + 64 + lane]) +
             (smem[j * 256 + 128 + lane] + smem[j * 256 + 192 + lane]);
  __syncthreads();   // conv region dead after this barrier

#pragma unroll
  for (int j = 0; j < 16; ++j) acc[j] += bo[j];
#pragma unroll
  for (int j = 0; j < 8; ++j) acc[16 + j] += bw[j];

  // softmax + mask fold (lane = pixel)
  float m = acc[16];
#pragma unroll
  for (int k = 1; k < K_; ++k) m = fmaxf(m, acc[16 + k]);
  float s = 0.f;
#pragma unroll
  for (int k = 0; k < K_; ++k) s += __expf(acc[16 + k] - m);
  const float fm = (mask[p0 + lane] != 0) ? 1.f : 0.f;
  const float inv = fm / s;
  const bool act = (fm != 0.f);

  // active-pixel compaction (identical across all 4 waves: lane = pixel)
  const unsigned long long mball = __ballot(act);
  const int A = __popcll(mball);
  const int aidx = __builtin_amdgcn_mbcnt_hi(
      (unsigned)(mball >> 32), __builtin_amdgcn_mbcnt_lo((unsigned)mball, 0));
  if (act) actl[aidx] = lane;                       // all waves write same values
  if (A > 0) {
    const int first = __ffsll((unsigned long long)mball) - 1;
    if (lane >= A) actl[lane] = first;              // sentinel pad (loads only)
  }

  const int hw = hw0 + lane;
  const int y = hw / W_;
  const int x = hw - y * W_;
  const int bHW = b * HW_;

  // records for this wave's 16 pixels (lanes 16wv..16wv+15 own pixel = lane)
  if ((lane >> 4) == wv) {
    const int pxl = lane;
#pragma unroll
    for (int k = 0; k < K_; ++k) {
      const float wtk = __expf(acc[16 + k] - m) * inv;
      const float px = (float)x + acc[2 * k];
      const float py = (float)y + acc[2 * k + 1];
      const float x0f = floorf(px), y0f = floorf(py);
      const float wx = px - x0f, wy = py - y0f;
      const int x0 = (int)x0f, y0 = (int)y0f;
      const int x1 = x0 + 1, y1 = y0 + 1;
      const bool vx0 = ((unsigned)x0 < (unsigned)W_);
      const bool vx1 = ((unsigned)x1 < (unsigned)W_);
      const bool vy0 = ((unsigned)y0 < (unsigned)H_);
      const bool vy1 = ((unsigned)y1 < (unsigned)H_);
      const int cx0 = min(max(x0, 0), W_ - 1), cx1 = min(max(x1, 0), W_ - 1);
      const int cy0 = min(max(y0, 0), H_ - 1), cy1 = min(max(y1, 0), H_ - 1);
      const float w00 = wtk * (1.f - wx) * (1.f - wy) * ((vx0 && vy0) ? 1.f : 0.f);
      const float w01 = wtk * wx * (1.f - wy) * ((vx1 && vy0) ? 1.f : 0.f);
      const float w10 = wtk * (1.f - wx) * wy * ((vx0 && vy1) ? 1.f : 0.f);
      const float w11 = wtk * wx * wy * ((vx1 && vy1) ? 1.f : 0.f);
      // byte offsets into bf16 NHWC (128B rows); masked -> offset 0, w=0
      const int o00 = act ? ((bHW + cy0 * W_ + cx0) << 7) : 0;
      const int o01 = act ? ((bHW + cy0 * W_ + cx1) << 7) : 0;
      const int o10 = act ? ((bHW + cy1 * W_ + cx0) << 7) : 0;
      const int o11 = act ? ((bHW + cy1 * W_ + cx1) << 7) : 0;
      float4 ra, rb;
      ra.x = w00; ra.y = __int_as_float(o00);
      ra.z = w01; ra.w = __int_as_float(o01);
      rb.x = w10; rb.y = __int_as_float(o10);
      rb.z = w11; rb.w = __int_as_float(o11);
      rw4[(k * 2 + 0) * 64 + pxl] = ra;
      rw4[(k * 2 + 1) * 64 + pxl] = rb;
    }
  }

  // zero res rows (masked pixels keep zeros; active rows overwritten below)
#pragma unroll
  for (int j = 0; j < 17; ++j) {
    const int idx = j * 256 + tid;
    if (idx < 4160) resb[idx] = 0.f;
  }
  __syncthreads();   // records + actlist + zeros visible to all waves

  // ---- phase C: compacted gather. lane = (pg, cg): 8 px x 8 ch-groups of 8. ----
  const int pg = lane >> 3;            // 0..7
  const int cg = lane & 7;             // channel group of 8 (bf16)
  const int cgb = cg * 16;             // byte offset within a pixel's 128B row
  const char* ftb = (const char*)ws;
  const int tot = (A + 7) >> 3;        // passes over active pixels (uniform)

#define ACC8(V, WT)                                                        \
  do {                                                                     \
    rr[0] = fmaf(WT, __uint_as_float((V).x << 16), rr[0]);                 \
    rr[1] = fmaf(WT, __uint_as_float((V).x & 0xffff0000u), rr[1]);         \
    rr[2] = fmaf(WT, __uint_as_float((V).y << 16), rr[2]);                 \
    rr[3] = fmaf(WT, __uint_as_float((V).y & 0xffff0000u), rr[3]);         \
    rr[4] = fmaf(WT, __uint_as_float((V).z << 16), rr[4]);                 \
    rr[5] = fmaf(WT, __uint_as_float((V).z & 0xffff0000u), rr[5]);         \
    rr[6] = fmaf(WT, __uint_as_float((V).w << 16), rr[6]);                 \
    rr[7] = fmaf(WT, __uint_as_float((V).w & 0xffff0000u), rr[7]);         \
  } while (0)

  for (int i = wv; i < tot; i += 4) {   // round-robin passes across waves
    const int gi = i * 8 + pg;
    const int pxl = actl[gi];           // sentinel-padded
    float rr[8];
#pragma unroll
    for (int j = 0; j < 8; ++j) rr[j] = 0.f;
#pragma unroll
    for (int k2 = 0; k2 < 4; ++k2) {    // k pair: 8 staged loads in flight
      const float4 ra0 = rw4[((2 * k2 + 0) * 2 + 0) * 64 + pxl];
      const float4 rb0 = rw4[((2 * k2 + 0) * 2 + 1) * 64 + pxl];
      const float4 ra1 = rw4[((2 * k2 + 1) * 2 + 0) * 64 + pxl];
      const float4 rb1 = rw4[((2 * k2 + 1) * 2 + 1) * 64 + pxl];
      const uint4 v0 = *(const uint4*)(ftb + (__float_as_int(ra0.y) + cgb));
      const uint4 v1 = *(const uint4*)(ftb + (__float_as_int(ra0.w) + cgb));
      const uint4 v2 = *(const uint4*)(ftb + (__float_as_int(rb0.y) + cgb));
      const uint4 v3 = *(const uint4*)(ftb + (__float_as_int(rb0.w) + cgb));
      const uint4 v4 = *(const uint4*)(ftb + (__float_as_int(ra1.y) + cgb));
      const uint4 v5 = *(const uint4*)(ftb + (__float_as_int(ra1.w) + cgb));
      const uint4 v6 = *(const uint4*)(ftb + (__float_as_int(rb1.y) + cgb));
      const uint4 v7 = *(const uint4*)(ftb + (__float_as_int(rb1.w) + cgb));
      ACC8(v0, ra0.x); ACC8(v1, ra0.z); ACC8(v2, rb0.x); ACC8(v3, rb0.z);
      ACC8(v4, ra1.x); ACC8(v5, ra1.z); ACC8(v6, rb1.x); ACC8(v7, rb1.z);
    }
    if (gi < A) {                       // sentinel passes don't write
      const int base = pxl * 65 + cg * 8;
#pragma unroll
      for (int j = 0; j < 8; ++j) resb[base + j] = rr[j];
    }
  }
#undef ACC8
  __syncthreads();

  // ---- phase D: epilogue, coalesced NCHW; feat from phase-A registers ----
#pragma unroll
  for (int cc = 0; cc < 16; ++cc) {
    const int c = wv * 16 + cc;
    const size_t off = bCHW + (size_t)c * HW_ + hw0 + lane;
    out[off] = fv[cc] + resb[lane * 65 + c];
  }
}

// =================== Fallback (ws-free, round-1 fused) ===================
__global__ __launch_bounds__(256) void fused_kernel(
    const float* __restrict__ feat, const int* __restrict__ mask,
    const float* __restrict__ Wo, const float* __restrict__ bo,
    const float* __restrict__ Ww, const float* __restrict__ bw,
    float* __restrict__ out) {
  const int p = blockIdx.x * blockDim.x + threadIdx.x;
  const int b = p / HW_;
  const int hw = p - b * HW_;
  const int y = hw / W_;
  const int x = hw - y * W_;
  const float* fb = feat + b * CHW_;
  float acc[24];
#pragma unroll
  for (int i = 0; i < 16; ++i) acc[i] = bo[i];
#pragma unroll
  for (int i = 0; i < 8; ++i) acc[16 + i] = bw[i];
#pragma unroll
  for (int c = 0; c < C_; ++c) {
    const float v = fb[c * HW_ + hw];
#pragma unroll
    for (int i = 0; i < 16; ++i) acc[i] = fmaf(Wo[i * C_ + c], v, acc[i]);
#pragma unroll
    for (int i = 0; i < 8; ++i) acc[16 + i] = fmaf(Ww[i * C_ + c], v, acc[16 + i]);
  }
  float m = acc[16];
#pragma unroll
  for (int k = 1; k < K_; ++k) m = fmaxf(m, acc[16 + k]);
  float wt[K_];
  float s = 0.f;
#pragma unroll
  for (int k = 0; k < K_; ++k) { wt[k] = __expf(acc[16 + k] - m); s += wt[k]; }
  const float fm = (mask[p] != 0) ? 1.f : 0.f;
  const float inv = fm / s;
#pragma unroll
  for (int k = 0; k < K_; ++k) wt[k] *= inv;
  float res[C_];
#pragma unroll
  for (int c = 0; c < C_; ++c) res[c] = 0.f;
  if (fm != 0.f) {
#pragma unroll
    for (int k = 0; k < K_; ++k) {
      const float px = (float)x + acc[2 * k];
      const float py = (float)y + acc[2 * k + 1];
      const float x0f = floorf(px), y0f = floorf(py);
      const float wx = px - x0f, wy = py - y0f;
      const int x0 = (int)x0f, y0 = (int)y0f;
      const int x1 = x0 + 1, y1 = y0 + 1;
      const bool vx0 = ((unsigned)x0 < (unsigned)W_);
      const bool vx1 = ((unsigned)x1 < (unsigned)W_);
      const bool vy0 = ((unsigned)y0 < (unsigned)H_);
      const bool vy1 = ((unsigned)y1 < (unsigned)H_);
      const int cx0 = min(max(x0, 0), W_ - 1), cx1 = min(max(x1, 0), W_ - 1);
      const int cy0 = min(max(y0, 0), H_ - 1), cy1 = min(max(y1, 0), H_ - 1);
      const float wk = wt[k];
      const float w00 = wk * (1.f - wx) * (1.f - wy) * ((vx0 && vy0) ? 1.f : 0.f);
      const float w01 = wk * wx * (1.f - wy) * ((vx1 && vy0) ? 1.f : 0.f);
      const float w10 = wk * (1.f - wx) * wy * ((vx0 && vy1) ? 1.f : 0.f);
      const float w11 = wk * wx * wy * ((vx1 && vy1) ? 1.f : 0.f);
      const int i00 = cy0 * W_ + cx0, i01 = cy0 * W_ + cx1;
      const int i10 = cy1 * W_ + cx0, i11 = cy1 * W_ + cx1;
#pragma unroll
      for (int c = 0; c < C_; ++c) {
        const float* fc = fb + c * HW_;
        res[c] += w00 * fc[i00] + w01 * fc[i01] + w10 * fc[i10] + w11 * fc[i11];
      }
    }
  }
#pragma unroll
  for (int c = 0; c < C_; ++c)
    out[b * CHW_ + c * HW_ + hw] = fb[c * HW_ + hw] + res[c];
}

extern "C" void kernel_launch(void* const* d_in, const int* in_sizes, int n_in,
                              void* d_out, int out_size, void* d_ws, size_t ws_size,
                              hipStream_t stream) {
  const float* feat = (const float*)d_in[0];
  const int* mask = (const int*)d_in[1];
  const float* Wo = (const float*)d_in[2];
  const float* bo = (const float*)d_in[3];
  const float* Ww = (const float*)d_in[4];
  const float* bw = (const float*)d_in[5];
  float* out = (float*)d_out;

  if (ws_size >= WS_NEED_) {
    unsigned short* ws = (unsigned short*)d_ws;
    hipLaunchKernelGGL(transpose16_kernel, dim3(NBLK_), dim3(256), 0, stream,
                       feat, ws);
    hipLaunchKernelGGL(fusedg_kernel, dim3(NBLK_), dim3(256), 0, stream,
                       feat, mask, Wo, bo, Ww, bw, ws, out);
  } else {
    hipLaunchKernelGGL(fused_kernel, dim3(NP_ / 256), dim3(256), 0, stream,
                       feat, mask, Wo, bo, Ww, bw, out);
  }
}